// Round 11
// baseline (343.714 us; speedup 1.0000x reference)
//
#include <hip/hip_runtime.h>

// VectorQuantizer: inputs [8,4096,64] f32, weight [8192,64] f32.
// Outputs concat: quantized_st [2097152] f32, loss [1] f32, indices [32768] f32.
//
// R15 = R14 (241us, passing) with merge+recheck+final fused into ONE tail
// kernel with zero cross-block data flow (each block owns 32 rows end-to-end:
// merge -> in-LDS final_idx -> np-exact rescan of its own flagged rows ->
// gather/STE/loss). This is NOT the unsound R10/R11 mega-fusion: the only
// cross-dispatch data (bestk/secd from argmin, packedW/wsq from prep) crosses
// a dispatch boundary, which is coherence-safe and proven by R6->R14.
// Removes rrk/sdone/rcount/rrows/final_idx buffers and 2 dispatches.
// prep + argmin byte-identical to R14 (argmin: 108.7us, MfmaUtil 41.6%).
// Recheck math inside the tail is R2's proven per-row scan: thread t scans
// codes t+256c ascending (strict < == np first-min), serial i=0..63 fmaf
// chain, d=(x2+wsq)-2s; combine via u64 key (ord(d)<<32|code) wave-min ->
// LDS -> thread 0 (= smallest dist, then smallest index: np tie-break).

typedef short bf16x8 __attribute__((ext_vector_type(8)));
typedef float f32x4  __attribute__((ext_vector_type(4)));

#define N_ROWS 32768
#define DIM 64
#define K_CODES 8192
#define KSPLIT 8
#define KCHUNK 1024
#define OUT_Q 0
#define OUT_LOSS 2097152
#define OUT_IDX 2097153
#define MARGIN 4e-4f
#define KEYMASK 0xFFFFFF80u
#define TROWS 32     // rows per tail block

// ---- helpers ----
__device__ __forceinline__ unsigned f2u_ord(float f) {
    unsigned u = __float_as_uint(f);
    return (u & 0x80000000u) ? ~u : (u | 0x80000000u);
}
__device__ __forceinline__ unsigned short bf16_rne(float f) {
    unsigned u = __float_as_uint(f);
    u += 0x7fffu + ((u >> 16) & 1u);
    return (unsigned short)(u >> 16);
}
__device__ __forceinline__ float bf16_to_f(unsigned short h) {
    return __uint_as_float(((unsigned)h) << 16);
}

// numpy pairwise_sum over 64 squared elements (exact np emulation)
__device__ __forceinline__ float np_pairwise_sq64(const float* v) {
    float r[8];
#pragma unroll
    for (int j = 0; j < 8; j++) r[j] = __fmul_rn(v[j], v[j]);
#pragma unroll
    for (int i = 8; i < 64; i += 8) {
#pragma unroll
        for (int j = 0; j < 8; j++)
            r[j] = __fadd_rn(r[j], __fmul_rn(v[i + j], v[i + j]));
    }
    return __fadd_rn(__fadd_rn(__fadd_rn(r[0], r[1]), __fadd_rn(r[2], r[3])),
                     __fadd_rn(__fadd_rn(r[4], r[5]), __fadd_rn(r[6], r[7])));
}

// ---------------- kernel 0: prep (wsq + wsqb + packedW + loss zero) ----------
__global__ __launch_bounds__(256) void vq_prep(const float* __restrict__ weight,
                                               float* __restrict__ wsq,
                                               float* __restrict__ wsqb,
                                               int4* __restrict__ packedW,
                                               float* __restrict__ loss_out) {
    int tid = threadIdx.x;
    if (blockIdx.x == 0 && tid == 0) *loss_out = 0.f;

    if (tid < 64) {
        int k = blockIdx.x * 64 + tid;
        float w[64];
        const float4* wp = (const float4*)(weight + (size_t)k * DIM);
#pragma unroll
        for (int i = 0; i < 16; i++) {
            float4 t = wp[i];
            w[4 * i] = t.x; w[4 * i + 1] = t.y; w[4 * i + 2] = t.z; w[4 * i + 3] = t.w;
        }
        float s = np_pairwise_sq64(w);
        wsq[k] = s;
        wsqb[k] = s + 8.0f;   // BIAS folded for the MFMA accumulator init
    }

    int wave = tid >> 6;
    int lane = tid & 63;
    int tile = blockIdx.x * 4 + wave;     // 0..511
    int code = tile * 16 + (lane & 15);
    int kq = (lane >> 4) * 8;
    const float* wr = weight + (size_t)code * DIM;

    union { bf16x8 v; int4 q; } hi0, hi1, lo0, lo1;
#pragma unroll
    for (int j = 0; j < 8; j++) {
        float a = -2.0f * wr[kq + j];
        unsigned short ha = bf16_rne(a);
        hi0.v[j] = (short)ha;
        lo0.v[j] = (short)bf16_rne(a - bf16_to_f(ha));
        float b = -2.0f * wr[32 + kq + j];
        unsigned short hb = bf16_rne(b);
        hi1.v[j] = (short)hb;
        lo1.v[j] = (short)bf16_rne(b - bf16_to_f(hb));
    }
    size_t base = (size_t)tile * 4 * 64;
    packedW[base + 0 * 64 + lane] = hi0.q;
    packedW[base + 1 * 64 + lane] = hi1.q;
    packedW[base + 2 * 64 + lane] = lo0.q;
    packedW[base + 3 * 64 + lane] = lo1.q;
}

// ---------------- kernel 1: MFMA argmin top-2 over a 1024-code chunk ----------
// grid (256, KSPLIT=8) x 256. Block: 128 rows; wave: 32 rows (2 row-tiles).
__global__ __launch_bounds__(256) void vq_argmin_mfma(const float* __restrict__ inp,
                                                      const int4* __restrict__ packedW,
                                                      const float* __restrict__ wsqb,
                                                      unsigned long long* __restrict__ bestk,
                                                      unsigned* __restrict__ secd) {
    __shared__ int4 sB[1024];   // 16 KB: two 8 KB buffers (2 code-tiles each)
    int wave = threadIdx.x >> 6;
    int lane = threadIdx.x & 63;
    int rbase = blockIdx.x * 128 + wave * 32;
    int kbase = blockIdx.y * KCHUNK;

    int kq = (lane >> 4) * 8;
    bf16x8 ah[2][2], al[2][2];   // [row-tile][k-chunk]
#pragma unroll
    for (int rt = 0; rt < 2; rt++) {
        const float* xp = inp + (size_t)(rbase + rt * 16 + (lane & 15)) * DIM;
#pragma unroll
        for (int kc = 0; kc < 2; kc++) {
            const float* xq = xp + kc * 32 + kq;
#pragma unroll
            for (int j = 0; j < 8; j++) {
                float a = xq[j];
                unsigned short h = bf16_rne(a);
                ah[rt][kc][j] = (short)h;
                al[rt][kc][j] = (short)bf16_rne(a - bf16_to_f(h));
            }
        }
    }

    unsigned best[8], sec[8];
#pragma unroll
    for (int s = 0; s < 8; s++) { best[s] = 0xFFFFFFFFu; sec[s] = 0xFFFFFFFFu; }

#define STAGE(buf, g) do {                                                        \
        const char* _src = (const char*)packedW +                                 \
            ((size_t)(kbase >> 4) + (size_t)(g) * 2) * 4096 + wave * 2048;        \
        char* _dst = (char*)sB + (buf) * 8192 + wave * 2048;                      \
        _Pragma("unroll")                                                         \
        for (int _i = 0; _i < 2; _i++)                                            \
            __builtin_amdgcn_global_load_lds(                                     \
                (const __attribute__((address_space(1))) unsigned int*)(_src + _i * 1024 + lane * 16), \
                (__attribute__((address_space(3))) unsigned int*)(_dst + _i * 1024), \
                16, 0, 0);                                                        \
    } while (0)

    STAGE(0, 0);
    __syncthreads();   // drains vmcnt(0): buf0 ready

    for (int g = 0; g < 32; g++) {
        int buf = g & 1;
        if (g + 1 < 32) STAGE(buf ^ 1, g + 1);   // issue next-group loads FIRST
        int lane_code = kbase + g * 32 + (lane & 15);
#pragma unroll
        for (int t = 0; t < 2; t++) {
            const int4* bp = sB + buf * 512 + t * 256;
            union { int4 q; bf16x8 v; } bh0, bh1, bl0, bl1;
            bh0.q = bp[0 * 64 + lane];
            bh1.q = bp[1 * 64 + lane];
            bl0.q = bp[2 * 64 + lane];
            bl1.q = bp[3 * 64 + lane];
            float wq = wsqb[lane_code + t * 16];
            unsigned tid7 = (unsigned)(g * 2 + t);   // 0..63 tile id in chunk
#pragma unroll
            for (int rt = 0; rt < 2; rt++) {
                f32x4 acc = {wq, wq, wq, wq};   // c = wsq + 8 - 2*dot, directly
                acc = __builtin_amdgcn_mfma_f32_16x16x32_bf16(ah[rt][0], bh0.v, acc, 0, 0, 0);
                acc = __builtin_amdgcn_mfma_f32_16x16x32_bf16(ah[rt][1], bh1.v, acc, 0, 0, 0);
                acc = __builtin_amdgcn_mfma_f32_16x16x32_bf16(al[rt][0], bh0.v, acc, 0, 0, 0);
                acc = __builtin_amdgcn_mfma_f32_16x16x32_bf16(al[rt][1], bh1.v, acc, 0, 0, 0);
                acc = __builtin_amdgcn_mfma_f32_16x16x32_bf16(ah[rt][0], bl0.v, acc, 0, 0, 0);
                acc = __builtin_amdgcn_mfma_f32_16x16x32_bf16(ah[rt][1], bl1.v, acc, 0, 0, 0);
#pragma unroll
                for (int r = 0; r < 4; r++) {
                    unsigned key = (__float_as_uint(acc[r]) & KEYMASK) | tid7;
                    int s = rt * 4 + r;
                    unsigned mx = best[s] > key ? best[s] : key;
                    sec[s] = sec[s] < mx ? sec[s] : mx;
                    best[s] = best[s] < key ? best[s] : key;
                }
            }
        }
        __syncthreads();
    }
#undef STAGE

    unsigned col[8];
#pragma unroll
    for (int s = 0; s < 8; s++) col[s] = lane & 15;
#pragma unroll
    for (int m = 1; m < 16; m <<= 1) {
#pragma unroll
        for (int s = 0; s < 8; s++) {
            unsigned ok = (unsigned)__shfl_xor((int)best[s], m, 64);
            unsigned os = (unsigned)__shfl_xor((int)sec[s], m, 64);
            unsigned oc = (unsigned)__shfl_xor((int)col[s], m, 64);
            unsigned mx = best[s] > ok ? best[s] : ok;
            unsigned mn2 = sec[s] < os ? sec[s] : os;
            sec[s] = mn2 < mx ? mn2 : mx;
            bool take = ok < best[s];
            best[s] = take ? ok : best[s];
            col[s] = take ? oc : col[s];
        }
    }
    if ((lane & 15) == 0) {
        int g4 = lane >> 4;
#pragma unroll
        for (int rt = 0; rt < 2; rt++)
#pragma unroll
            for (int r = 0; r < 4; r++) {
                int row = rbase + rt * 16 + g4 * 4 + r;
                int s = rt * 4 + r;
                int code = kbase + (int)(best[s] & 127u) * 16 + (int)col[s];
                bestk[(size_t)blockIdx.y * N_ROWS + row] =
                    ((unsigned long long)best[s] << 32) | (unsigned)code;
                secd[(size_t)blockIdx.y * N_ROWS + row] = sec[s];
            }
    }
}

// ---------------- kernel 2: fused merge + np-exact recheck + final -----------
// grid 1024 x 256. Block owns rows [bx*32, bx*32+32): merges the KSPLIT chunk
// results (idx kept in LDS), rescans its own flagged rows np-exactly with all
// 256 threads (serial over flagged rows), then does gather+STE+loss+idx-write
// for its 32 rows. No cross-block data flow at all.
__global__ __launch_bounds__(256) void vq_tail(const float* __restrict__ inp,
                                               const float* __restrict__ weight,
                                               const float* __restrict__ wsq,
                                               const unsigned long long* __restrict__ bestk,
                                               const unsigned* __restrict__ secd,
                                               float* __restrict__ out) {
    __shared__ int idx_lds[TROWS];
    __shared__ int rowlist[TROWS];
    __shared__ int nf_s;
    __shared__ float xs[DIM];
    __shared__ float x2s;
    __shared__ unsigned long long wk[4];
    __shared__ float red[4];

    int tid = threadIdx.x;
    int lane = tid & 63;
    int wave = tid >> 6;
    int rbase = blockIdx.x * TROWS;

    if (tid == 0) nf_s = 0;
    __syncthreads();

    // ---- Phase A: merge KSPLIT chunks (proven R14 vq_merge math) ----
    if (tid < TROWS) {
        int row = rbase + tid;
        unsigned long long ks[KSPLIT];
        unsigned ss[KSPLIT];
#pragma unroll
        for (int c = 0; c < KSPLIT; c++) {
            ks[c] = bestk[(size_t)c * N_ROWS + row];
            ss[c] = secd[(size_t)c * N_ROWS + row];
        }
        unsigned long long k1 = ks[0];
#pragma unroll
        for (int c = 1; c < KSPLIT; c++) k1 = (ks[c] < k1) ? ks[c] : k1;
        unsigned d2 = 0xFFFFFFFFu;
#pragma unroll
        for (int c = 0; c < KSPLIT; c++) {
            if (ks[c] != k1) {
                unsigned b = (unsigned)(ks[c] >> 32);
                d2 = b < d2 ? b : d2;
            }
            d2 = ss[c] < d2 ? ss[c] : d2;
        }
        idx_lds[tid] = (int)(k1 & 0xffffffffull);
        float f1 = __uint_as_float(((unsigned)(k1 >> 32)) & KEYMASK);
        float f2 = __uint_as_float(d2 & KEYMASK);
        if (f2 - f1 < MARGIN) {
            int slot = atomicAdd(&nf_s, 1);
            rowlist[slot] = tid;       // local row id
        }
    }
    __syncthreads();
    int nf = nf_s;

    // ---- Phase B: np-exact rescan of flagged rows (R2-proven scan) ----
    for (int f = 0; f < nf; ++f) {
        int lr = rowlist[f];
        int row = rbase + lr;
        if (tid < DIM) xs[tid] = inp[(size_t)row * DIM + tid];
        __syncthreads();
        if (tid == 0) x2s = np_pairwise_sq64(xs);
        __syncthreads();
        float x2 = x2s;

        float bd = 3.402823466e+38f;
        int bi = 0x7fffffff;
#pragma unroll 1
        for (int c = 0; c < K_CODES / 256; ++c) {
            int code = c * 256 + tid;
            const float* wp = weight + (size_t)code * DIM;
            float s = 0.f;
#pragma unroll
            for (int i = 0; i < DIM; i++) s = __builtin_fmaf(xs[i], wp[i], s);
            float t1 = __fadd_rn(x2, wsq[code]);
            float d  = __fsub_rn(t1, __fmul_rn(2.0f, s));
            if (d < bd) { bd = d; bi = code; }
        }
        unsigned long long key =
            ((unsigned long long)f2u_ord(bd) << 32) | (unsigned)bi;
#pragma unroll
        for (int m = 1; m < 64; m <<= 1) {
            unsigned hi = (unsigned)(key >> 32), lo = (unsigned)key;
            unsigned ohi = (unsigned)__shfl_xor((int)hi, m, 64);
            unsigned olo = (unsigned)__shfl_xor((int)lo, m, 64);
            unsigned long long o = ((unsigned long long)ohi << 32) | olo;
            key = o < key ? o : key;
        }
        if (lane == 0) wk[wave] = key;
        __syncthreads();
        if (tid == 0) {
            unsigned long long k = wk[0];
#pragma unroll
            for (int w = 1; w < 4; w++) k = wk[w] < k ? wk[w] : k;
            idx_lds[lr] = (int)(k & 0xffffffffull);
        }
        __syncthreads();
    }

    // ---- Phase C: gather + STE + loss + index (from LDS idx) ----
    float lp = 0.f;
#pragma unroll
    for (int i = 0; i < (TROWS * 16) / 256; ++i) {   // 2 float4 per thread
        int e = i * 256 + tid;
        int lr = e >> 4;
        int sub = e & 15;
        int row = rbase + lr;
        int idx = idx_lds[lr];

        float4 x = ((const float4*)inp)[(size_t)row * 16 + sub];
        float4 w = ((const float4*)weight)[(size_t)idx * 16 + sub];

        float4 q;
        q.x = x.x + (w.x - x.x);
        q.y = x.y + (w.y - x.y);
        q.z = x.z + (w.z - x.z);
        q.w = x.w + (w.w - x.w);
        ((float4*)(out + OUT_Q))[(size_t)row * 16 + sub] = q;

        if (sub == 0) out[OUT_IDX + row] = (float)idx;

        float dx = w.x - x.x, dy = w.y - x.y, dz = w.z - x.z, dw = w.w - x.w;
        lp += dx * dx + dy * dy + dz * dz + dw * dw;
    }
#pragma unroll
    for (int o = 32; o > 0; o >>= 1) lp += __shfl_down(lp, o, 64);
    if (lane == 0) red[wave] = lp;
    __syncthreads();
    if (tid == 0) {
        float bs = red[0] + red[1] + red[2] + red[3];
        atomicAdd(out + OUT_LOSS, bs * (0.25f / 2097152.f));
    }
}

extern "C" void kernel_launch(void* const* d_in, const int* in_sizes, int n_in,
                              void* d_out, int out_size, void* d_ws, size_t ws_size,
                              hipStream_t stream) {
    const float* inp = (const float*)d_in[0];
    const float* weight = (const float*)d_in[1];
    float* out = (float*)d_out;

    char* p = (char*)d_ws;
    unsigned long long* bestk = (unsigned long long*)p; p += (size_t)KSPLIT * N_ROWS * 8; // 2 MB
    unsigned* secd  = (unsigned*)p;            p += (size_t)KSPLIT * N_ROWS * 4;          // 1 MB
    float* wsq      = (float*)p;               p += (size_t)K_CODES * 4;                  // 32 KB
    float* wsqb     = (float*)p;               p += (size_t)K_CODES * 4;                  // 32 KB
    int4* packedW   = (int4*)p;                p += (size_t)512 * 4 * 64 * 16;            // 2 MB

    vq_prep<<<128, 256, 0, stream>>>(weight, wsq, wsqb, packedW, out + OUT_LOSS);
    vq_argmin_mfma<<<dim3(N_ROWS / 128, KSPLIT), 256, 0, stream>>>(
        inp, packedW, wsqb, bestk, secd);
    vq_tail<<<N_ROWS / TROWS, 256, 0, stream>>>(inp, weight, wsq, bestk, secd, out);
}